// Round 11
// baseline (116.455 us; speedup 1.0000x reference)
//
#include <hip/hip_runtime.h>
#include <hip/hip_bf16.h>

#define NN   4096
#define FIN  512
#define FOUT 64
#define NH   8
#define ALPHA 0.2f
#define ROWS 64
#define LOG2E 1.4426950408889634f

typedef __attribute__((ext_vector_type(8))) short bf16x8;
typedef __attribute__((ext_vector_type(4))) float f32x4;

__device__ __forceinline__ unsigned short f2bf(float x) {
    unsigned u = __float_as_uint(x);
    return (unsigned short)((u + 0x7fffu + ((u >> 16) & 1u)) >> 16);  // RNE
}

__device__ __forceinline__ unsigned pk2(float a, float b) {
    union { __hip_bfloat162 h2; unsigned u; } cv;
    cv.h2 = __float22bfloat162_rn(float2{a, b});   // low 16 = a (RNE)
    return cv.u;
}

// ---------------------------------------------------------------------------
// KB: adj -> 64-bit masks. No LDS (full occupancy), 8 loads in flight per
// wave, ballots stored pairwise by lane 0. (Proven R8 kernel.)
// ---------------------------------------------------------------------------
__global__ __launch_bounds__(256) void kb(const int* __restrict__ adj,
                                          unsigned long long* __restrict__ bits) {
    const int wv   = blockIdx.x * 4 + (threadIdx.x >> 6);
    const int lane = threadIdx.x & 63;
    const int base = wv * 32;
    #pragma unroll
    for (int r = 0; r < 4; ++r) {
        int v0 = adj[(size_t)(base + r*8 + 0) * 64 + lane];
        int v1 = adj[(size_t)(base + r*8 + 1) * 64 + lane];
        int v2 = adj[(size_t)(base + r*8 + 2) * 64 + lane];
        int v3 = adj[(size_t)(base + r*8 + 3) * 64 + lane];
        int v4 = adj[(size_t)(base + r*8 + 4) * 64 + lane];
        int v5 = adj[(size_t)(base + r*8 + 5) * 64 + lane];
        int v6 = adj[(size_t)(base + r*8 + 6) * 64 + lane];
        int v7 = adj[(size_t)(base + r*8 + 7) * 64 + lane];
        unsigned long long m0 = __ballot(v0 > 0);
        unsigned long long m1 = __ballot(v1 > 0);
        unsigned long long m2 = __ballot(v2 > 0);
        unsigned long long m3 = __ballot(v3 > 0);
        unsigned long long m4 = __ballot(v4 > 0);
        unsigned long long m5 = __ballot(v5 > 0);
        unsigned long long m6 = __ballot(v6 > 0);
        unsigned long long m7 = __ballot(v7 > 0);
        if (lane == 0) {
            ulonglong2* dst = (ulonglong2*)&bits[base + r*8];
            dst[0] = {m0, m1};
            dst[1] = {m2, m3};
            dst[2] = {m4, m5};
            dst[3] = {m6, m7};
        }
    }
}

// ---------------------------------------------------------------------------
// KG: Wh GEMM + f1/f2 (prescaled by log2e) + bf16 WhTs (tiled+swizzled)
// epilogue. Proven kernel, unchanged.
// ---------------------------------------------------------------------------
__global__ __launch_bounds__(256) void kg(const float* __restrict__ x,
                                          const float* __restrict__ W,
                                          const float* __restrict__ aw,
                                          unsigned short* __restrict__ WhTs,
                                          float* __restrict__ f1,
                                          float* __restrict__ f2) {
    __shared__ float As[16][68];
    __shared__ float Bs[16][68];
    __shared__ unsigned short Tb[64][80];
    __shared__ float r1[64][16];
    __shared__ float r2[64][16];
    const int t = threadIdx.x;
    const int bx   = blockIdx.x;             // 0..511
    const int h    = bx >> 6;
    const int nti  = bx & 63;
    const int row0 = nti * 64;
    const int tr = t >> 4, tc = t & 15;
    const int ar = t >> 2, ak = t & 3;
    const int bk = t >> 4, bo = t & 15;
    const float* WH = W + (size_t)h * FIN * FOUT;
    float acc[4][4] = {};

    for (int k0i = 0; k0i < FIN; k0i += 16) {
        __syncthreads();
        float4 av = *(const float4*)&x[(size_t)(row0 + ar) * FIN + k0i + ak * 4];
        As[ak*4+0][ar] = av.x; As[ak*4+1][ar] = av.y;
        As[ak*4+2][ar] = av.z; As[ak*4+3][ar] = av.w;
        *(float4*)&Bs[bk][bo*4] =
            *(const float4*)&WH[(size_t)(k0i + bk) * FOUT + bo*4];
        __syncthreads();
        #pragma unroll
        for (int kk = 0; kk < 16; ++kk) {
            float4 a4 = *(const float4*)&As[kk][tr*4];
            float4 b4 = *(const float4*)&Bs[kk][tc*4];
            float a[4] = {a4.x, a4.y, a4.z, a4.w};
            float b[4] = {b4.x, b4.y, b4.z, b4.w};
            #pragma unroll
            for (int i = 0; i < 4; ++i)
                #pragma unroll
                for (int j = 0; j < 4; ++j)
                    acc[i][j] = fmaf(a[i], b[j], acc[i][j]);
        }
    }

    float a1v[4], a2v[4];
    #pragma unroll
    for (int j = 0; j < 4; ++j) {
        a1v[j] = aw[h * 2 * FOUT + tc*4 + j];
        a2v[j] = aw[h * 2 * FOUT + FOUT + tc*4 + j];
    }
    #pragma unroll
    for (int i = 0; i < 4; ++i) {
        float s1 = 0.f, s2 = 0.f;
        #pragma unroll
        for (int j = 0; j < 4; ++j) {
            s1 = fmaf(acc[i][j], a1v[j], s1);
            s2 = fmaf(acc[i][j], a2v[j], s2);
            Tb[tc*4 + j][tr*4 + i] = f2bf(acc[i][j]);
        }
        r1[tr*4 + i][tc] = s1;
        r2[tr*4 + i][tc] = s2;
    }
    __syncthreads();
    if (t < 64) {
        float s1 = 0.f, s2 = 0.f;
        #pragma unroll
        for (int k = 0; k < 16; ++k) { s1 += r1[t][k]; s2 += r2[t][k]; }
        f1[h * NN + row0 + t] = s1 * LOG2E;   // prescale: exp(x)=exp2(x*log2e)
        f2[h * NN + row0 + t] = s2 * LOG2E;   // (lrelu commutes with pos scale)
    }
    unsigned char* tileB = (unsigned char*)(WhTs + ((size_t)(h * 64) + nti) * 4096);
    #pragma unroll
    for (int i = 0; i < 2; ++i) {
        int c = t + i * 256;
        int o = c >> 3, nch = c & 7;
        *(uint4*)(tileB + o * 128 + ((nch * 16) ^ ((o & 7) << 4))) =
            *(const uint4*)&Tb[o][nch * 8];
    }
}

// ---------------------------------------------------------------------------
// K3: fused masked softmax + PV (bf16 MFMA), j-split. Proven 2-barrier
// template. ROWS=64: grid 2048 blocks -> 8 blocks/CU (LDS 16 KB, ~45 VGPR)
// to raise occupancy from 4 blocks/CU (R10 was grid-capped at 31%).
// Denominator via MFMA with constant ones-B fragment.
// ---------------------------------------------------------------------------
__global__ __launch_bounds__(256, 8) void k3_attn(
        const unsigned long long* __restrict__ bits,
        const unsigned short* __restrict__ WhTs,
        const float* __restrict__ f1, const float* __restrict__ f2,
        float* __restrict__ pnum, float* __restrict__ pden) {
    __shared__ unsigned char psB[ROWS * 128];   // 8 KB
    __shared__ unsigned char wsB[8192];         // 8 KB
    const int t    = threadIdx.x;
    const int lane = t & 63, wid = t >> 6;
    const int h    = blockIdx.y;
    const int row0 = blockIdx.x * ROWS;
    const int js   = blockIdx.z, JS = gridDim.z;
    const int ntile = (NN / 64) / JS;
    const int nt0   = js * ntile;
    const int pr   = t >> 2, psub = t & 3;     // row 0..63, j-quarter 0..3
    const float f1r = f1[h * NN + row0 + pr];
    const float* f2h = f2 + h * NN;
    const unsigned long long* bitsRow = bits + (size_t)(row0 + pr) * 64;
    const unsigned short* WTS = WhTs + (size_t)h * 64 * 4096;
    const int prswz = (pr & 7) << 4;
    f32x4 acc[4] = {};
    f32x4 accd = {};
    const bf16x8 ones = {0x3F80, 0x3F80, 0x3F80, 0x3F80,
                         0x3F80, 0x3F80, 0x3F80, 0x3F80};   // bf16 1.0 x8

    uint4 wreg0, wreg1;
    auto loadW = [&](int nti, uint4& w0, uint4& w1) {
        const uint4* gt = (const uint4*)(WTS + (size_t)nti * 4096);
        w0 = gt[t];
        w1 = gt[t + 256];
    };
    loadW(nt0, wreg0, wreg1);

    const int kb2 = (lane >> 4) * 16;
    for (int it = 0; it < ntile; ++it) {
        const int nti = nt0 + it;
        __syncthreads();                       // prev MFMA done reading tiles
        *(uint4*)&wsB[t * 16]        = wreg0;
        *(uint4*)&wsB[t * 16 + 4096] = wreg1;
        {
            unsigned msk = (unsigned)(bitsRow[nti] >> (psub << 4)) & 0xFFFFu;
            const float* f2c = f2h + nti * 64 + psub * 16;
            #pragma unroll
            for (int half = 0; half < 2; ++half) {
                unsigned pk[4];
                #pragma unroll
                for (int c2 = 0; c2 < 2; ++c2) {
                    const int c = half * 2 + c2;
                    float4 f4 = *(const float4*)&f2c[c * 4];
                    float e0 = f1r + f4.x, e1 = f1r + f4.y;
                    float e2 = f1r + f4.z, e3 = f1r + f4.w;
                    e0 = fmaxf(e0, ALPHA * e0); e1 = fmaxf(e1, ALPHA * e1);
                    e2 = fmaxf(e2, ALPHA * e2); e3 = fmaxf(e3, ALPHA * e3);
                    const int b = c * 4;
                    float p0 = ((msk >> (b+0)) & 1u) ? __builtin_amdgcn_exp2f(e0) : 0.f;
                    float p1 = ((msk >> (b+1)) & 1u) ? __builtin_amdgcn_exp2f(e1) : 0.f;
                    float p2 = ((msk >> (b+2)) & 1u) ? __builtin_amdgcn_exp2f(e2) : 0.f;
                    float p3 = ((msk >> (b+3)) & 1u) ? __builtin_amdgcn_exp2f(e3) : 0.f;
                    pk[c2*2+0] = pk2(p0, p1);
                    pk[c2*2+1] = pk2(p2, p3);
                }
                uint4 w = {pk[0], pk[1], pk[2], pk[3]};
                *(uint4*)&psB[pr * 128 + ((psub*32 + half*16) ^ prswz)] = w;
            }
        }
        if (it + 1 < ntile) loadW(nti + 1, wreg0, wreg1);
        __syncthreads();                       // tiles visible
        {
            const int arw  = wid * 16 + (lane & 15);
            const int aswz = (arw & 7) << 4;
            #pragma unroll
            for (int ks = 0; ks < 2; ++ks) {
                bf16x8 af = *(const bf16x8*)&psB[arw * 128 + ((ks*64 + kb2) ^ aswz)];
                accd = __builtin_amdgcn_mfma_f32_16x16x32_bf16(af, ones, accd, 0, 0, 0);
                #pragma unroll
                for (int cf = 0; cf < 4; ++cf) {
                    int brw = cf * 16 + (lane & 15);
                    bf16x8 bfr = *(const bf16x8*)&wsB[brw * 128 + ((ks*64 + kb2) ^ ((brw & 7) << 4))];
                    acc[cf] = __builtin_amdgcn_mfma_f32_16x16x32_bf16(af, bfr, acc[cf], 0, 0, 0);
                }
            }
        }
    }

    float* pn = pnum + (((size_t)js * NH + h) * NN + row0) * 64;
    #pragma unroll
    for (int cf = 0; cf < 4; ++cf) {
        int o = cf * 16 + (lane & 15);
        #pragma unroll
        for (int rg = 0; rg < 4; ++rg) {
            int rl = wid * 16 + (lane >> 4) * 4 + rg;
            pn[(size_t)rl * 64 + o] = acc[cf][rg];
        }
    }
    if ((lane & 15) == 0) {                    // col-0 lanes hold den[row]
        float* pd = pden + ((size_t)js * NH + h) * NN + row0;
        #pragma unroll
        for (int rg = 0; rg < 4; ++rg)
            pd[wid * 16 + (lane >> 4) * 4 + rg] = accd[rg];
    }
}

// ---------------------------------------------------------------------------
// K4: reduce over JS slices + normalize.
// ---------------------------------------------------------------------------
__global__ __launch_bounds__(256) void k4_red(const float* __restrict__ pnum,
                                              const float* __restrict__ pden,
                                              float* __restrict__ out, int JS) {
    const int idx = blockIdx.x * 256 + threadIdx.x;   // 0..524287
    const int h   = idx >> 16;
    const int rem = idx & 65535;
    const int n   = rem >> 4;
    const int o4  = (rem & 15) * 4;
    float4 s = {0.f, 0.f, 0.f, 0.f};
    float  d = 0.f;
    for (int js = 0; js < JS; ++js) {
        const float* p = pnum + (((size_t)js * NH + h) * NN + n) * 64 + o4;
        float4 v = *(const float4*)p;
        s.x += v.x; s.y += v.y; s.z += v.z; s.w += v.w;
        d += pden[((size_t)js * NH + h) * NN + n];
    }
    float inv = 1.0f / d;
    float4 r = {s.x * inv, s.y * inv, s.z * inv, s.w * inv};
    *(float4*)&out[(size_t)n * (NH * FOUT) + h * FOUT + o4] = r;
}

extern "C" void kernel_launch(void* const* d_in, const int* in_sizes, int n_in,
                              void* d_out, int out_size, void* d_ws, size_t ws_size,
                              hipStream_t stream) {
    const float* x   = (const float*)d_in[0];
    const int*   adj = (const int*)d_in[1];
    const float* W   = (const float*)d_in[2];
    const float* a   = (const float*)d_in[3];
    float* outp = (float*)d_out;

    // workspace layout
    unsigned short* WhTs = (unsigned short*)d_ws;                   // 4 MB (tiled)
    float* f1 = (float*)(WhTs + (size_t)NH * 64 * NN);              // 128 KB
    float* f2 = f1 + NH * NN;                                       // 128 KB
    unsigned long long* bits = (unsigned long long*)(f2 + NH * NN); // 2 MB
    float* pnum = (float*)(bits + (size_t)NN * 64);
    const size_t baseBytes  = (size_t)(pnum - (float*)d_ws) * 4;
    const size_t sliceBytes = (size_t)NH * NN * 65 * 4;             // num+den per slice
    int JS = 1;
    if (ws_size >= baseBytes + 4 * sliceBytes) JS = 4;
    else if (ws_size >= baseBytes + 2 * sliceBytes) JS = 2;
    float* pden = pnum + (size_t)JS * NH * NN * 64;

    kb     <<<dim3(2048),            256, 0, stream>>>(adj, bits);
    kg     <<<dim3(512),             256, 0, stream>>>(x, W, a, WhTs, f1, f2);
    k3_attn<<<dim3(NN/ROWS, NH, JS), 256, 0, stream>>>(bits, WhTs, f1, f2, pnum, pden);
    k4_red <<<dim3(NN*NH*FOUT/4/256), 256, 0, stream>>>(pnum, pden, outp, JS);
}

// Round 12
// 112.335 us; speedup vs baseline: 1.0367x; 1.0367x over previous
//
#include <hip/hip_runtime.h>
#include <hip/hip_bf16.h>

#define NN   4096
#define FIN  512
#define FOUT 64
#define NH   8
#define ALPHA 0.2f
#define ROWS 128
#define LOG2E 1.4426950408889634f

typedef __attribute__((ext_vector_type(8))) short bf16x8;
typedef __attribute__((ext_vector_type(4))) float f32x4;

__device__ __forceinline__ unsigned short f2bf(float x) {
    unsigned u = __float_as_uint(x);
    return (unsigned short)((u + 0x7fffu + ((u >> 16) & 1u)) >> 16);  // RNE
}

__device__ __forceinline__ unsigned pk2(float a, float b) {
    union { __hip_bfloat162 h2; unsigned u; } cv;
    cv.h2 = __float22bfloat162_rn(float2{a, b});   // low 16 = a (RNE)
    return cv.u;
}

// ---------------------------------------------------------------------------
// KB: adj -> 64-bit masks. No LDS (full occupancy), 8 loads in flight per
// wave, ballots stored pairwise by lane 0. (Proven R8 kernel.)
// ---------------------------------------------------------------------------
__global__ __launch_bounds__(256) void kb(const int* __restrict__ adj,
                                          unsigned long long* __restrict__ bits) {
    const int wv   = blockIdx.x * 4 + (threadIdx.x >> 6);
    const int lane = threadIdx.x & 63;
    const int base = wv * 32;
    #pragma unroll
    for (int r = 0; r < 4; ++r) {
        int v0 = adj[(size_t)(base + r*8 + 0) * 64 + lane];
        int v1 = adj[(size_t)(base + r*8 + 1) * 64 + lane];
        int v2 = adj[(size_t)(base + r*8 + 2) * 64 + lane];
        int v3 = adj[(size_t)(base + r*8 + 3) * 64 + lane];
        int v4 = adj[(size_t)(base + r*8 + 4) * 64 + lane];
        int v5 = adj[(size_t)(base + r*8 + 5) * 64 + lane];
        int v6 = adj[(size_t)(base + r*8 + 6) * 64 + lane];
        int v7 = adj[(size_t)(base + r*8 + 7) * 64 + lane];
        unsigned long long m0 = __ballot(v0 > 0);
        unsigned long long m1 = __ballot(v1 > 0);
        unsigned long long m2 = __ballot(v2 > 0);
        unsigned long long m3 = __ballot(v3 > 0);
        unsigned long long m4 = __ballot(v4 > 0);
        unsigned long long m5 = __ballot(v5 > 0);
        unsigned long long m6 = __ballot(v6 > 0);
        unsigned long long m7 = __ballot(v7 > 0);
        if (lane == 0) {
            ulonglong2* dst = (ulonglong2*)&bits[base + r*8];
            dst[0] = {m0, m1};
            dst[1] = {m2, m3};
            dst[2] = {m4, m5};
            dst[3] = {m6, m7};
        }
    }
}

// ---------------------------------------------------------------------------
// KG: Wh GEMM + f1/f2 (prescaled by log2e) + bf16 WhTs (tiled+swizzled)
// epilogue. Proven kernel, unchanged.
// ---------------------------------------------------------------------------
__global__ __launch_bounds__(256) void kg(const float* __restrict__ x,
                                          const float* __restrict__ W,
                                          const float* __restrict__ aw,
                                          unsigned short* __restrict__ WhTs,
                                          float* __restrict__ f1,
                                          float* __restrict__ f2) {
    __shared__ float As[16][68];
    __shared__ float Bs[16][68];
    __shared__ unsigned short Tb[64][80];
    __shared__ float r1[64][16];
    __shared__ float r2[64][16];
    const int t = threadIdx.x;
    const int bx   = blockIdx.x;             // 0..511
    const int h    = bx >> 6;
    const int nti  = bx & 63;
    const int row0 = nti * 64;
    const int tr = t >> 4, tc = t & 15;
    const int ar = t >> 2, ak = t & 3;
    const int bk = t >> 4, bo = t & 15;
    const float* WH = W + (size_t)h * FIN * FOUT;
    float acc[4][4] = {};

    for (int k0i = 0; k0i < FIN; k0i += 16) {
        __syncthreads();
        float4 av = *(const float4*)&x[(size_t)(row0 + ar) * FIN + k0i + ak * 4];
        As[ak*4+0][ar] = av.x; As[ak*4+1][ar] = av.y;
        As[ak*4+2][ar] = av.z; As[ak*4+3][ar] = av.w;
        *(float4*)&Bs[bk][bo*4] =
            *(const float4*)&WH[(size_t)(k0i + bk) * FOUT + bo*4];
        __syncthreads();
        #pragma unroll
        for (int kk = 0; kk < 16; ++kk) {
            float4 a4 = *(const float4*)&As[kk][tr*4];
            float4 b4 = *(const float4*)&Bs[kk][tc*4];
            float a[4] = {a4.x, a4.y, a4.z, a4.w};
            float b[4] = {b4.x, b4.y, b4.z, b4.w};
            #pragma unroll
            for (int i = 0; i < 4; ++i)
                #pragma unroll
                for (int j = 0; j < 4; ++j)
                    acc[i][j] = fmaf(a[i], b[j], acc[i][j]);
        }
    }

    float a1v[4], a2v[4];
    #pragma unroll
    for (int j = 0; j < 4; ++j) {
        a1v[j] = aw[h * 2 * FOUT + tc*4 + j];
        a2v[j] = aw[h * 2 * FOUT + FOUT + tc*4 + j];
    }
    #pragma unroll
    for (int i = 0; i < 4; ++i) {
        float s1 = 0.f, s2 = 0.f;
        #pragma unroll
        for (int j = 0; j < 4; ++j) {
            s1 = fmaf(acc[i][j], a1v[j], s1);
            s2 = fmaf(acc[i][j], a2v[j], s2);
            Tb[tc*4 + j][tr*4 + i] = f2bf(acc[i][j]);
        }
        r1[tr*4 + i][tc] = s1;
        r2[tr*4 + i][tc] = s2;
    }
    __syncthreads();
    if (t < 64) {
        float s1 = 0.f, s2 = 0.f;
        #pragma unroll
        for (int k = 0; k < 16; ++k) { s1 += r1[t][k]; s2 += r2[t][k]; }
        f1[h * NN + row0 + t] = s1 * LOG2E;   // prescale: exp(x)=exp2(x*log2e)
        f2[h * NN + row0 + t] = s2 * LOG2E;   // (lrelu commutes with pos scale)
    }
    unsigned char* tileB = (unsigned char*)(WhTs + ((size_t)(h * 64) + nti) * 4096);
    #pragma unroll
    for (int i = 0; i < 2; ++i) {
        int c = t + i * 256;
        int o = c >> 3, nch = c & 7;
        *(uint4*)(tileB + o * 128 + ((nch * 16) ^ ((o & 7) << 4))) =
            *(const uint4*)&Tb[o][nch * 8];
    }
}

// ---------------------------------------------------------------------------
// K3: fused masked softmax + PV (bf16 MFMA), j-split. Proven 2-barrier
// template. ROWS=128 (R10 geometry) but 512-thread / 8-wave blocks:
// 1024 blocks = 4 blocks/CU x 8 waves = 32 waves/CU (100%), vs R10's 16.
// Each wave owns a 16-row band in the MFMA phase (acc[4]+accd, ~48 VGPR).
// Denominator via MFMA with constant ones-B fragment.
// ---------------------------------------------------------------------------
__global__ __launch_bounds__(512, 8) void k3_attn(
        const unsigned long long* __restrict__ bits,
        const unsigned short* __restrict__ WhTs,
        const float* __restrict__ f1, const float* __restrict__ f2,
        float* __restrict__ pnum, float* __restrict__ pden) {
    __shared__ unsigned char psB[ROWS * 128];   // 16 KB
    __shared__ unsigned char wsB[8192];         //  8 KB
    const int t    = threadIdx.x;
    const int lane = t & 63, wid = t >> 6;      // 8 waves
    const int h    = blockIdx.y;
    const int row0 = blockIdx.x * ROWS;
    const int js   = blockIdx.z, JS = gridDim.z;
    const int ntile = (NN / 64) / JS;
    const int nt0   = js * ntile;
    const int pr   = t >> 2, psub = t & 3;     // row 0..127, j-quarter 0..3
    const float f1r = f1[h * NN + row0 + pr];
    const float* f2h = f2 + h * NN;
    const unsigned long long* bitsRow = bits + (size_t)(row0 + pr) * 64;
    const unsigned short* WTS = WhTs + (size_t)h * 64 * 4096;
    const int prswz = (pr & 7) << 4;
    f32x4 acc[4] = {};
    f32x4 accd = {};
    const bf16x8 ones = {0x3F80, 0x3F80, 0x3F80, 0x3F80,
                         0x3F80, 0x3F80, 0x3F80, 0x3F80};   // bf16 1.0 x8

    uint4 wreg;
    auto loadW = [&](int nti, uint4& w0) {
        w0 = ((const uint4*)(WTS + (size_t)nti * 4096))[t];   // 512 x 16B = 8 KB
    };
    loadW(nt0, wreg);

    const int kb2 = (lane >> 4) * 16;
    for (int it = 0; it < ntile; ++it) {
        const int nti = nt0 + it;
        __syncthreads();                       // prev MFMA done reading tiles
        *(uint4*)&wsB[t * 16] = wreg;
        {
            unsigned msk = (unsigned)(bitsRow[nti] >> (psub << 4)) & 0xFFFFu;
            const float* f2c = f2h + nti * 64 + psub * 16;
            #pragma unroll
            for (int half = 0; half < 2; ++half) {
                unsigned pk[4];
                #pragma unroll
                for (int c2 = 0; c2 < 2; ++c2) {
                    const int c = half * 2 + c2;
                    float4 f4 = *(const float4*)&f2c[c * 4];
                    float e0 = f1r + f4.x, e1 = f1r + f4.y;
                    float e2 = f1r + f4.z, e3 = f1r + f4.w;
                    e0 = fmaxf(e0, ALPHA * e0); e1 = fmaxf(e1, ALPHA * e1);
                    e2 = fmaxf(e2, ALPHA * e2); e3 = fmaxf(e3, ALPHA * e3);
                    const int b = c * 4;
                    float p0 = ((msk >> (b+0)) & 1u) ? __builtin_amdgcn_exp2f(e0) : 0.f;
                    float p1 = ((msk >> (b+1)) & 1u) ? __builtin_amdgcn_exp2f(e1) : 0.f;
                    float p2 = ((msk >> (b+2)) & 1u) ? __builtin_amdgcn_exp2f(e2) : 0.f;
                    float p3 = ((msk >> (b+3)) & 1u) ? __builtin_amdgcn_exp2f(e3) : 0.f;
                    pk[c2*2+0] = pk2(p0, p1);
                    pk[c2*2+1] = pk2(p2, p3);
                }
                uint4 w = {pk[0], pk[1], pk[2], pk[3]};
                *(uint4*)&psB[pr * 128 + ((psub*32 + half*16) ^ prswz)] = w;
            }
        }
        if (it + 1 < ntile) loadW(nti + 1, wreg);
        __syncthreads();                       // tiles visible
        {
            const int arw  = wid * 16 + (lane & 15);
            const int aswz = (arw & 7) << 4;
            #pragma unroll
            for (int ks = 0; ks < 2; ++ks) {
                bf16x8 af = *(const bf16x8*)&psB[arw * 128 + ((ks*64 + kb2) ^ aswz)];
                accd = __builtin_amdgcn_mfma_f32_16x16x32_bf16(af, ones, accd, 0, 0, 0);
                #pragma unroll
                for (int cf = 0; cf < 4; ++cf) {
                    int brw = cf * 16 + (lane & 15);
                    bf16x8 bfr = *(const bf16x8*)&wsB[brw * 128 + ((ks*64 + kb2) ^ ((brw & 7) << 4))];
                    acc[cf] = __builtin_amdgcn_mfma_f32_16x16x32_bf16(af, bfr, acc[cf], 0, 0, 0);
                }
            }
        }
    }

    float* pn = pnum + (((size_t)js * NH + h) * NN + row0) * 64;
    #pragma unroll
    for (int cf = 0; cf < 4; ++cf) {
        int o = cf * 16 + (lane & 15);
        #pragma unroll
        for (int rg = 0; rg < 4; ++rg) {
            int rl = wid * 16 + (lane >> 4) * 4 + rg;
            pn[(size_t)rl * 64 + o] = acc[cf][rg];
        }
    }
    if ((lane & 15) == 0) {                    // col-0 lanes hold den[row]
        float* pd = pden + ((size_t)js * NH + h) * NN + row0;
        #pragma unroll
        for (int rg = 0; rg < 4; ++rg)
            pd[wid * 16 + (lane >> 4) * 4 + rg] = accd[rg];
    }
}

// ---------------------------------------------------------------------------
// K4: reduce over JS slices + normalize.
// ---------------------------------------------------------------------------
__global__ __launch_bounds__(256) void k4_red(const float* __restrict__ pnum,
                                              const float* __restrict__ pden,
                                              float* __restrict__ out, int JS) {
    const int idx = blockIdx.x * 256 + threadIdx.x;   // 0..524287
    const int h   = idx >> 16;
    const int rem = idx & 65535;
    const int n   = rem >> 4;
    const int o4  = (rem & 15) * 4;
    float4 s = {0.f, 0.f, 0.f, 0.f};
    float  d = 0.f;
    for (int js = 0; js < JS; ++js) {
        const float* p = pnum + (((size_t)js * NH + h) * NN + n) * 64 + o4;
        float4 v = *(const float4*)p;
        s.x += v.x; s.y += v.y; s.z += v.z; s.w += v.w;
        d += pden[((size_t)js * NH + h) * NN + n];
    }
    float inv = 1.0f / d;
    float4 r = {s.x * inv, s.y * inv, s.z * inv, s.w * inv};
    *(float4*)&out[(size_t)n * (NH * FOUT) + h * FOUT + o4] = r;
}

extern "C" void kernel_launch(void* const* d_in, const int* in_sizes, int n_in,
                              void* d_out, int out_size, void* d_ws, size_t ws_size,
                              hipStream_t stream) {
    const float* x   = (const float*)d_in[0];
    const int*   adj = (const int*)d_in[1];
    const float* W   = (const float*)d_in[2];
    const float* a   = (const float*)d_in[3];
    float* outp = (float*)d_out;

    // workspace layout
    unsigned short* WhTs = (unsigned short*)d_ws;                   // 4 MB (tiled)
    float* f1 = (float*)(WhTs + (size_t)NH * 64 * NN);              // 128 KB
    float* f2 = f1 + NH * NN;                                       // 128 KB
    unsigned long long* bits = (unsigned long long*)(f2 + NH * NN); // 2 MB
    float* pnum = (float*)(bits + (size_t)NN * 64);
    const size_t baseBytes  = (size_t)(pnum - (float*)d_ws) * 4;
    const size_t sliceBytes = (size_t)NH * NN * 65 * 4;             // num+den per slice
    int JS = 1;
    if (ws_size >= baseBytes + 4 * sliceBytes) JS = 4;
    else if (ws_size >= baseBytes + 2 * sliceBytes) JS = 2;
    float* pden = pnum + (size_t)JS * NH * NN * 64;

    kb     <<<dim3(2048),            256, 0, stream>>>(adj, bits);
    kg     <<<dim3(512),             256, 0, stream>>>(x, W, a, WhTs, f1, f2);
    k3_attn<<<dim3(NN/ROWS, NH, JS), 512, 0, stream>>>(bits, WhTs, f1, f2, pnum, pden);
    k4_red <<<dim3(NN*NH*FOUT/4/256), 256, 0, stream>>>(pnum, pden, outp, JS);
}